// Round 3
// baseline (327.748 us; speedup 1.0000x reference)
//
#include <hip/hip_runtime.h>
#include <hip/hip_bf16.h>

typedef unsigned short u16;
typedef unsigned int   u32;
typedef unsigned long long u64;
typedef __attribute__((ext_vector_type(8))) short bf16x8;
typedef __attribute__((ext_vector_type(4))) float f32x4;
typedef __attribute__((ext_vector_type(16))) float f32x16;

#define MFMA16(a,b,c) __builtin_amdgcn_mfma_f32_16x16x32_bf16((a),(b),(c),0,0,0)
#define MFMA32(a,b,c) __builtin_amdgcn_mfma_f32_32x32x16_bf16((a),(b),(c),0,0,0)

#define GLD16(gp, lp) __builtin_amdgcn_global_load_lds( \
    (const __attribute__((address_space(1))) void*)(gp), \
    (__attribute__((address_space(3))) void*)(lp), 16, 0, 0)

__device__ inline u32 pkbf(float a, float b) {
  __hip_bfloat16 ha = __float2bfloat16(a), hb = __float2bfloat16(b);
  return (u32)(*(u16*)&ha) | ((u32)(*(u16*)&hb) << 16);
}
__device__ inline float b2f(u16 x) {
  __hip_bfloat16 h; *(u16*)&h = x; return __bfloat162float(h);
}

// ---------------------------------------------------------------- cast f32->bf16
__global__ __launch_bounds__(256) void cast_f32_bf16(const float* __restrict__ src,
                                                     u16* __restrict__ dst, int n4) {
  int i = blockIdx.x * 256 + threadIdx.x;
  if (i >= n4) return;
  float4 v = reinterpret_cast<const float4*>(src)[i];
  u32 lo = pkbf(v.x, v.y);
  u32 hi = pkbf(v.z, v.w);
  uint2 pk; pk.x = lo; pk.y = hi;
  reinterpret_cast<uint2*>(dst)[i] = pk;
}

// ---------------------------------------------------------------- GEMM C = A * B^T
__device__ inline void cstore(u16* C, size_t i, float v) {
  __hip_bfloat16 h = __float2bfloat16(v); C[i] = *(u16*)&h;
}
__device__ inline void cstore(float* C, size_t i, float v) { C[i] = v; }

template<typename OutT>
__global__ __launch_bounds__(256) void gemm_bt(const u16* __restrict__ A,
                                               const u16* __restrict__ B,
                                               OutT* __restrict__ C,
                                               int M, int N, int K) {
  __shared__ u16 As[128 * 32];
  __shared__ u16 Bs[128 * 32];
  const int t = threadIdx.x;
  const int lane = t & 63, wid = t >> 6;
  const int l15 = lane & 15, l4 = lane >> 4;
  const int wr = wid >> 1, wc = wid & 1;

  // XCD-aware bijective swizzle (grid % 8 == 0)
  const int nwg = gridDim.x * gridDim.y;
  int lid = blockIdx.y * gridDim.x + blockIdx.x;
  lid = (lid & 7) * (nwg >> 3) + (lid >> 3);
  const int m0 = (lid / gridDim.x) * 128, n0 = (lid % gridDim.x) * 128;

  const int srow = t >> 2, scol = (t & 3) << 3;
  const u16* Ag = A + (size_t)(m0 + srow) * K + scol;
  const u16* Bg = B + (size_t)(n0 + srow) * K + scol;
  u16* As_d  = &As[srow * 32 + scol];
  u16* As_d2 = &As[(srow + 64) * 32 + scol];
  u16* Bs_d  = &Bs[srow * 32 + scol];
  u16* Bs_d2 = &Bs[(srow + 64) * 32 + scol];

  const int fra = wr * 64 + l15;
  const int frb = wc * 64 + l15;
  const int fk  = l4 << 3;

  f32x4 acc[4][4] = {};
  for (int k0 = 0; k0 < K; k0 += 32) {
    __syncthreads();
    GLD16(Ag + k0,                 As_d);
    GLD16(Ag + (size_t)64*K + k0,  As_d2);
    GLD16(Bg + k0,                 Bs_d);
    GLD16(Bg + (size_t)64*K + k0,  Bs_d2);
    __syncthreads();
    bf16x8 af[4], bfr[4];
#pragma unroll
    for (int m = 0; m < 4; ++m) af[m]  = *(const bf16x8*)&As[(fra + m*16)*32 + fk];
#pragma unroll
    for (int n = 0; n < 4; ++n) bfr[n] = *(const bf16x8*)&Bs[(frb + n*16)*32 + fk];
#pragma unroll
    for (int m = 0; m < 4; ++m)
#pragma unroll
      for (int n = 0; n < 4; ++n)
        acc[m][n] = MFMA16(af[m], bfr[n], acc[m][n]);
  }
  const int crow = m0 + wr * 64 + (l4 << 2);
  const int ccol = n0 + wc * 64 + l15;
#pragma unroll
  for (int m = 0; m < 4; ++m)
#pragma unroll
    for (int n = 0; n < 4; ++n)
#pragma unroll
      for (int r = 0; r < 4; ++r)
        cstore(C, (size_t)(crow + m*16 + r) * N + (ccol + n*16), acc[m][n][r]);
}

// ---------------------------------------------------------------- RMSNorm + RoPE
__global__ __launch_bounds__(256) void rmsrope_kernel(u16* __restrict__ qkv) {
  const int t = threadIdx.x;
  const int lane = t & 63;
  const int gw = blockIdx.x * 4 + (t >> 6);
  const int row = gw / 20;
  const int hd = gw - row * 20;
  const int col = (hd < 16) ? hd * 128 : 2048 + (hd - 16) * 128;
  const size_t base = (size_t)row * 3072 + col;
  float x1 = b2f(qkv[base + lane]);
  float x2 = b2f(qkv[base + 64 + lane]);
  float ss = x1 * x1 + x2 * x2;
#pragma unroll
  for (int off = 32; off >= 1; off >>= 1) ss += __shfl_xor(ss, off, 64);
  const float sc = rsqrtf(ss * (1.0f / 128.0f) + 1e-6f);
  const int pos = row & 2047;
  const float inv_freq = exp2f(-(float)lane * (13.287712379549449f / 64.0f));
  float sn, cs;
  sincosf((float)pos * inv_freq, &sn, &cs);
  const float a = x1 * sc, b2 = x2 * sc;
  __hip_bfloat16 o1 = __float2bfloat16(a * cs - b2 * sn);
  __hip_bfloat16 o2 = __float2bfloat16(a * sn + b2 * cs);
  qkv[base + lane] = *(u16*)&o1;
  qkv[base + 64 + lane] = *(u16*)&o2;
}

// ---------------------------------------------------------------- flash attention
// 768 blocks: rank = bid>>5 (24 work items, balanced triples {r,r+8,r+16}=34
// tiles), bh = bid&31. qt<8 unsplit (half=2); qt>=8 split in 2 KV halves,
// partials merged by attn_merge. 4 waves x 32 q; 32x32x16 MFMA; swapped QK^T;
// PV with k-slot-permuted V^T so P C-regs feed B-operand with NO shuffles.
// K double-buffered (GLD16, pre-swizzled src), V single-buffered (reg-staged).
__device__ __constant__ unsigned char QT_TAB[24] =
  {15,7,14,14,13,6,12,11, 15,13,12,10,10,9,11,5, 0,1,2,3,8,9,8,4};
__device__ __constant__ unsigned char HALF_TAB[24] =
  {0,2,0,1,1,2,1,1, 1,0,0,0,1,0,0,2, 2,2,2,2,0,1,1,2};

__global__ __launch_bounds__(256, 3) void attn_kernel(const u16* __restrict__ qkv,
                                                      u16* __restrict__ ao,
                                                      u16* __restrict__ pO,
                                                      float* __restrict__ pml) {
  __shared__ u16 Ks[2][64 * 128];   // [k][d], 16B chunks XORed by k&7
  __shared__ u16 Vt[128 * 64];      // [d][k-permuted], chunks XORed by d&7

  const int t = threadIdx.x;
  const int lane = t & 63, w = t >> 6;
  const int l31 = lane & 31, hi = lane >> 5;

  const int bid = blockIdx.x;
  const int rank = bid >> 5, bh = bid & 31;
  const int b = bh >> 4, h = bh & 15;
  const int qt = QT_TAB[rank], half = HALF_TAB[rank];
  const int q0 = qt * 128;
  const int kvh = h >> 2;
  const int kcol = 2048 + kvh * 128, vcol = 2560 + kvh * 128;
  const int t0 = (half == 1) ? (qt + 1) : 0;
  const int t1 = (half == 0) ? (qt + 1) : 2 * (qt + 1);
  const int qrow = q0 + w * 32 + l31;

  // Q fragments (B operand): col=q, k = st*16 + hi*8 + e
  bf16x8 qf[8];
  {
    const u16* qp = qkv + (size_t)(b * 2048 + qrow) * 3072 + h * 128 + hi * 8;
#pragma unroll
    for (int st = 0; st < 8; ++st) qf[st] = *(const bf16x8*)(qp + st * 16);
  }

  f32x16 o[4];
#pragma unroll
  for (int dt = 0; dt < 4; ++dt)
#pragma unroll
    for (int i = 0; i < 16; ++i) o[dt][i] = 0.f;
  float m2 = -INFINITY, l = 0.f;

  const int jv = t & 15, dc = t >> 4;         // V staging: rows 4jv..+3, d=dc*8..+7
  const int krow_s = t >> 4, kchk = t & 15;   // K staging
  const int vc_ = 2 * (jv >> 2) + (jv & 1);   // permuted chunk base
  const int vsub_ = ((jv >> 1) & 1) << 2;

#define STAGE_K(kb_, buf_) do {                                               \
    const size_t rb_ = (size_t)(b * 2048 + (kb_) * 64);                       \
    _Pragma("unroll")                                                         \
    for (int j_ = 0; j_ < 4; ++j_) {                                          \
      const int row_ = j_ * 16 + krow_s;                                      \
      GLD16(qkv + (rb_ + row_) * 3072 + kcol + ((kchk ^ (row_ & 7)) << 3),    \
            &Ks[buf_][(j_ * 256 + t) << 3]);                                  \
    } } while (0)

#define LOAD_V(kb_, vr_) do {                                                 \
    const u16* vp_ = qkv + (size_t)(b * 2048 + (kb_) * 64 + 4 * jv) * 3072    \
                     + vcol + dc * 8;                                         \
    vr_[0] = *(const bf16x8*)vp_;                                             \
    vr_[1] = *(const bf16x8*)(vp_ + 3072);                                    \
    vr_[2] = *(const bf16x8*)(vp_ + 6144);                                    \
    vr_[3] = *(const bf16x8*)(vp_ + 9216);                                    \
  } while (0)

  // k-slot-permuted V^T write: k=4jv+r lands at position 16(jv>>2)+8(jv&1)+
  // 4((jv>>1)&1)+r in row d; chunk XOR-swizzled by d&7 (d&7 == i here).
#define WRITE_V(vr_) do {                                                     \
    _Pragma("unroll")                                                         \
    for (int i_ = 0; i_ < 8; ++i_) {                                          \
      const int d_ = dc * 8 + i_;                                             \
      u64 val_ = (u64)(u16)vr_[0][i_] | ((u64)(u16)vr_[1][i_] << 16)          \
               | ((u64)(u16)vr_[2][i_] << 32) | ((u64)(u16)vr_[3][i_] << 48); \
      *(u64*)&Vt[d_ * 64 + (((vc_ ^ i_) << 3) + vsub_)] = val_;               \
    } } while (0)

  // prologue: stage tile t0
  {
    bf16x8 v0[4];
    LOAD_V(t0, v0);
    STAGE_K(t0, 0);
    WRITE_V(v0);
  }

  const float sc2 = 0.08838834764831845f * 1.44269504088896340f;  // scale*log2e

  for (int kb = t0; kb < t1; ++kb) {
    const int cur = (kb - t0) & 1;
    __syncthreads();                 // K[cur] GLD drained; Vt(kb) written
    const bool have_next = (kb + 1 < t1);
    bf16x8 vnext[4];
    if (have_next) {
      LOAD_V(kb + 1, vnext);
      STAGE_K(kb + 1, cur ^ 1);
    }
    const bool active = (kb * 64 <= q0 + w * 32 + 31);

    bf16x8 pa[4];
    if (active) {
      // ---- S^T = K Q^T  (rows k, cols q)
      f32x16 s0, s1;
#pragma unroll
      for (int i = 0; i < 16; ++i) { s0[i] = 0.f; s1[i] = 0.f; }
      const int kbase  = l31 * 128;
      const int kbase2 = (32 + l31) * 128;
      const int ksw = l31 & 7;
      __builtin_amdgcn_s_setprio(1);
#pragma unroll
      for (int st = 0; st < 8; ++st) {
        const int c = ((2 * st + hi) ^ ksw) << 3;
        bf16x8 ka  = *(const bf16x8*)&Ks[cur][kbase + c];
        bf16x8 kb2 = *(const bf16x8*)&Ks[cur][kbase2 + c];
        s0 = MFMA32(ka,  qf[st], s0);
        s1 = MFMA32(kb2, qf[st], s1);
      }
      __builtin_amdgcn_s_setprio(0);
      // ---- mask + scale (exp2 domain), row max
      float pm = -INFINITY;
      const bool nomask = (kb * 64 + 63) <= (q0 + w * 32);
      if (nomask) {
#pragma unroll
        for (int i = 0; i < 16; ++i) {
          s0[i] *= sc2; s1[i] *= sc2;
          pm = fmaxf(pm, fmaxf(s0[i], s1[i]));
        }
      } else {
#pragma unroll
        for (int i = 0; i < 16; ++i) {
          const int kr = kb * 64 + (i & 3) + 8 * (i >> 2) + 4 * hi;
          s0[i] = (kr <= qrow)      ? s0[i] * sc2 : -INFINITY;
          s1[i] = (kr + 32 <= qrow) ? s1[i] * sc2 : -INFINITY;
          pm = fmaxf(pm, fmaxf(s0[i], s1[i]));
        }
      }
      pm = fmaxf(pm, __shfl_xor(pm, 32));
      // ---- defer-max rescale
      if (!__all(pm <= m2 + 8.f)) {
        const float m2n = fmaxf(m2, pm);
        const float fc = exp2f(m2 - m2n);
        m2 = m2n; l *= fc;
#pragma unroll
        for (int dt = 0; dt < 4; ++dt)
#pragma unroll
          for (int i = 0; i < 16; ++i) o[dt][i] *= fc;
      }
      // ---- P = exp2(z - m2), per-half row sum (cross-half sum deferred)
      float sum = 0.f;
#pragma unroll
      for (int i = 0; i < 16; ++i) { s0[i] = exp2f(s0[i] - m2); sum += s0[i]; }
#pragma unroll
      for (int i = 0; i < 16; ++i) { s1[i] = exp2f(s1[i] - m2); sum += s1[i]; }
      l += sum;
      // ---- P C-regs -> B-operand directly (k-slot permutation, no shuffles)
      union PB { u32 wd[4]; bf16x8 v; };
      PB pb0, pb1, pb2, pb3;
#pragma unroll
      for (int q = 0; q < 4; ++q) {
        pb0.wd[q] = pkbf(s0[2*q],     s0[2*q + 1]);
        pb1.wd[q] = pkbf(s0[8 + 2*q], s0[8 + 2*q + 1]);
        pb2.wd[q] = pkbf(s1[2*q],     s1[2*q + 1]);
        pb3.wd[q] = pkbf(s1[8 + 2*q], s1[8 + 2*q + 1]);
      }
      pa[0] = pb0.v; pa[1] = pb1.v; pa[2] = pb2.v; pa[3] = pb3.v;
      // ---- O^T += V^T P  (rows d, cols q)
      __builtin_amdgcn_s_setprio(1);
#pragma unroll
      for (int dt = 0; dt < 4; ++dt) {
        const int vrow = (dt * 32 + l31) * 64;
        const int dsw = l31 & 7;
#pragma unroll
        for (int ks = 0; ks < 4; ++ks) {
          bf16x8 va = *(const bf16x8*)&Vt[vrow + (((2 * ks + hi) ^ dsw) << 3)];
          o[dt] = MFMA32(va, pa[ks], o[dt]);
        }
      }
      __builtin_amdgcn_s_setprio(0);
    }
    __syncthreads();                 // all waves done reading Vt
    if (have_next) WRITE_V(vnext);
  }

  // ---- epilogue
  const float l_tot = l + __shfl_xor(l, 32);
  const float inv = 1.f / l_tot;
  if (half == 2) {
    const size_t ob = (size_t)(b * 2048 + qrow) * 2048 + h * 128 + 4 * hi;
#pragma unroll
    for (int dt = 0; dt < 4; ++dt)
#pragma unroll
      for (int m = 0; m < 4; ++m) {
        u64 val = 0;
#pragma unroll
        for (int r = 0; r < 4; ++r) {
          __hip_bfloat16 hb = __float2bfloat16(o[dt][4*m + r] * inv);
          val |= (u64)(*(u16*)&hb) << (16 * r);
        }
        *(u64*)&ao[ob + dt * 32 + 8 * m] = val;
      }
  } else {
    const int p = ((bh * 8) + (qt - 8)) * 2 + half;
    const int lrow = w * 32 + l31;
    u16* po = pO + (size_t)p * 16384 + lrow * 128 + 4 * hi;
#pragma unroll
    for (int dt = 0; dt < 4; ++dt)
#pragma unroll
      for (int m = 0; m < 4; ++m) {
        u64 val = 0;
#pragma unroll
        for (int r = 0; r < 4; ++r) {
          __hip_bfloat16 hb = __float2bfloat16(o[dt][4*m + r] * inv);
          val |= (u64)(*(u16*)&hb) << (16 * r);
        }
        *(u64*)&po[dt * 32 + 8 * m] = val;
      }
    if (hi == 0) {
      pml[(p * 128 + lrow) * 2]     = m2;
      pml[(p * 128 + lrow) * 2 + 1] = l_tot;
    }
  }
#undef STAGE_K
#undef LOAD_V
#undef WRITE_V
}

// ---------------------------------------------------------------- merge partials
// block = (b*16+h)*8 + (qt-8); 256 thr: thread -> (row = t>>1, d-half = t&1).
__global__ __launch_bounds__(256) void attn_merge(const u16* __restrict__ pO,
                                                  const float* __restrict__ pml,
                                                  u16* __restrict__ ao) {
  const int blk = blockIdx.x, t = threadIdx.x;
  const int row = t >> 1, dh = (t & 1) << 6;
  const int p0 = blk * 2, p1 = p0 + 1;
  const float m0 = pml[(p0 * 128 + row) * 2];
  const float l0 = pml[(p0 * 128 + row) * 2 + 1];
  const float m1 = pml[(p1 * 128 + row) * 2];
  const float l1 = pml[(p1 * 128 + row) * 2 + 1];
  const float ms = fmaxf(m0, m1);
  float w0 = l0 * exp2f(m0 - ms), w1 = l1 * exp2f(m1 - ms);
  const float inv = 1.f / (w0 + w1);
  w0 *= inv; w1 *= inv;
  const int b = blk >> 7, h = (blk >> 3) & 15, qt8 = blk & 7;
  const u16* o0 = pO + (size_t)p0 * 16384 + row * 128 + dh;
  const u16* o1 = pO + (size_t)p1 * 16384 + row * 128 + dh;
  u16* dst = ao + (size_t)(b * 2048 + (qt8 + 8) * 128 + row) * 2048 + h * 128 + dh;
#pragma unroll
  for (int c = 0; c < 64; c += 8) {
    bf16x8 a = *(const bf16x8*)(o0 + c);
    bf16x8 bq = *(const bf16x8*)(o1 + c);
    bf16x8 outv;
#pragma unroll
    for (int r = 0; r < 8; ++r) {
      __hip_bfloat16 hb =
          __float2bfloat16(w0 * b2f((u16)a[r]) + w1 * b2f((u16)bq[r]));
      outv[r] = *(short*)&hb;
    }
    *(bf16x8*)(dst + c) = outv;
  }
}

// ---------------------------------------------------------------- launch
extern "C" void kernel_launch(void* const* d_in, const int* in_sizes, int n_in,
                              void* d_out, int out_size, void* d_ws, size_t ws_size,
                              hipStream_t stream) {
  const float* x  = (const float*)d_in[0];
  const float* wq = (const float*)d_in[2];
  const float* wk = (const float*)d_in[3];
  const float* wv = (const float*)d_in[4];
  const float* wo = (const float*)d_in[5];
  float* out = (float*)d_out;

  u16* xb   = (u16*)d_ws;                       // x bf16   [4096][2048]
  u16* wqkv = xb + (size_t)8388608;             // W bf16   [3072][2048]
  u16* qkv  = wqkv + (size_t)6291456;           // qkv      [4096][3072]
  u16* pO   = qkv + (size_t)12582912;           // partials 512 x 128 x 128 bf16
  float* pml = (float*)(pO + (size_t)8388608);  // 512 x 128 x 2 f32
  u16* ao   = xb;                               // attn out (reuse xb)
  u16* wob  = wqkv;                             // wo bf16 (reuse wqkv)

  cast_f32_bf16<<<8192, 256, 0, stream>>>(x,  xb,   2097152);
  cast_f32_bf16<<<4096, 256, 0, stream>>>(wq, wqkv, 1048576);
  cast_f32_bf16<<<1024, 256, 0, stream>>>(wk, wqkv + (size_t)4194304, 262144);
  cast_f32_bf16<<<1024, 256, 0, stream>>>(wv, wqkv + (size_t)5242880, 262144);

  gemm_bt<u16><<<dim3(24, 32), 256, 0, stream>>>(xb, wqkv, qkv, 4096, 3072, 2048);

  cast_f32_bf16<<<4096, 256, 0, stream>>>(wo, wob, 1048576);

  rmsrope_kernel<<<20480, 256, 0, stream>>>(qkv);

  attn_kernel<<<768, 256, 0, stream>>>(qkv, ao, pO, pml);
  attn_merge<<<256, 256, 0, stream>>>(pO, pml, ao);

  gemm_bt<float><<<dim3(16, 32), 256, 0, stream>>>(ao, wob, out, 4096, 2048, 2048);
}

// Round 4
// 247.592 us; speedup vs baseline: 1.3237x; 1.3237x over previous
//
#include <hip/hip_runtime.h>
#include <hip/hip_bf16.h>

typedef unsigned short u16;
typedef unsigned int   u32;
typedef unsigned long long u64;
typedef __attribute__((ext_vector_type(8))) short bf16x8;
typedef __attribute__((ext_vector_type(4))) float f32x4;
typedef __attribute__((ext_vector_type(16))) float f32x16;

#define MFMA16(a,b,c) __builtin_amdgcn_mfma_f32_16x16x32_bf16((a),(b),(c),0,0,0)
#define MFMA32(a,b,c) __builtin_amdgcn_mfma_f32_32x32x16_bf16((a),(b),(c),0,0,0)

#define GLD16(gp, lp) __builtin_amdgcn_global_load_lds( \
    (const __attribute__((address_space(1))) void*)(gp), \
    (__attribute__((address_space(3))) void*)(lp), 16, 0, 0)

__device__ inline u32 pkbf(float a, float b) {
  __hip_bfloat16 ha = __float2bfloat16(a), hb = __float2bfloat16(b);
  return (u32)(*(u16*)&ha) | ((u32)(*(u16*)&hb) << 16);
}
__device__ inline float b2f(u16 x) {
  __hip_bfloat16 h; *(u16*)&h = x; return __bfloat162float(h);
}

// ---------------------------------------------------------------- cast f32->bf16
__global__ __launch_bounds__(256) void cast_f32_bf16(const float* __restrict__ src,
                                                     u16* __restrict__ dst, int n4) {
  int i = blockIdx.x * 256 + threadIdx.x;
  if (i >= n4) return;
  float4 v = reinterpret_cast<const float4*>(src)[i];
  uint2 pk; pk.x = pkbf(v.x, v.y); pk.y = pkbf(v.z, v.w);
  reinterpret_cast<uint2*>(dst)[i] = pk;
}

// ---------------------------------------------------------------- GEMM C = A * B^T
__device__ inline void cstore(u16* C, size_t i, float v) {
  __hip_bfloat16 h = __float2bfloat16(v); C[i] = *(u16*)&h;
}
__device__ inline void cstore(float* C, size_t i, float v) { C[i] = v; }

template<typename OutT>
__global__ __launch_bounds__(256) void gemm_bt(const u16* __restrict__ A,
                                               const u16* __restrict__ B,
                                               OutT* __restrict__ C,
                                               int M, int N, int K) {
  __shared__ u16 As[128 * 32];
  __shared__ u16 Bs[128 * 32];
  const int t = threadIdx.x;
  const int lane = t & 63, wid = t >> 6;
  const int l15 = lane & 15, l4 = lane >> 4;
  const int wr = wid >> 1, wc = wid & 1;

  // XCD-aware bijective swizzle (grid % 8 == 0)
  const int nwg = gridDim.x * gridDim.y;
  int lid = blockIdx.y * gridDim.x + blockIdx.x;
  lid = (lid & 7) * (nwg >> 3) + (lid >> 3);
  const int m0 = (lid / gridDim.x) * 128, n0 = (lid % gridDim.x) * 128;

  const int srow = t >> 2, scol = (t & 3) << 3;
  const u16* Ag = A + (size_t)(m0 + srow) * K + scol;
  const u16* Bg = B + (size_t)(n0 + srow) * K + scol;
  u16* As_d  = &As[srow * 32 + scol];
  u16* As_d2 = &As[(srow + 64) * 32 + scol];
  u16* Bs_d  = &Bs[srow * 32 + scol];
  u16* Bs_d2 = &Bs[(srow + 64) * 32 + scol];

  const int fra = wr * 64 + l15;
  const int frb = wc * 64 + l15;
  const int fk  = l4 << 3;

  f32x4 acc[4][4] = {};
  for (int k0 = 0; k0 < K; k0 += 32) {
    __syncthreads();
    GLD16(Ag + k0,                 As_d);
    GLD16(Ag + (size_t)64*K + k0,  As_d2);
    GLD16(Bg + k0,                 Bs_d);
    GLD16(Bg + (size_t)64*K + k0,  Bs_d2);
    __syncthreads();
    bf16x8 af[4], bfr[4];
#pragma unroll
    for (int m = 0; m < 4; ++m) af[m]  = *(const bf16x8*)&As[(fra + m*16)*32 + fk];
#pragma unroll
    for (int n = 0; n < 4; ++n) bfr[n] = *(const bf16x8*)&Bs[(frb + n*16)*32 + fk];
#pragma unroll
    for (int m = 0; m < 4; ++m)
#pragma unroll
      for (int n = 0; n < 4; ++n)
        acc[m][n] = MFMA16(af[m], bfr[n], acc[m][n]);
  }
  const int crow = m0 + wr * 64 + (l4 << 2);
  const int ccol = n0 + wc * 64 + l15;
#pragma unroll
  for (int m = 0; m < 4; ++m)
#pragma unroll
    for (int n = 0; n < 4; ++n)
#pragma unroll
      for (int r = 0; r < 4; ++r)
        cstore(C, (size_t)(crow + m*16 + r) * N + (ccol + n*16), acc[m][n][r]);
}

// ---------------------------------------------------------------- RMSNorm + RoPE
__global__ __launch_bounds__(256) void rmsrope_kernel(u16* __restrict__ qkv) {
  const int t = threadIdx.x;
  const int lane = t & 63;
  const int gw = blockIdx.x * 4 + (t >> 6);
  const int row = gw / 20;
  const int hd = gw - row * 20;
  const int col = (hd < 16) ? hd * 128 : 2048 + (hd - 16) * 128;
  const size_t base = (size_t)row * 3072 + col;
  float x1 = b2f(qkv[base + lane]);
  float x2 = b2f(qkv[base + 64 + lane]);
  float ss = x1 * x1 + x2 * x2;
#pragma unroll
  for (int off = 32; off >= 1; off >>= 1) ss += __shfl_xor(ss, off, 64);
  const float sc = rsqrtf(ss * (1.0f / 128.0f) + 1e-6f);
  const int pos = row & 2047;
  const float inv_freq = exp2f(-(float)lane * (13.287712379549449f / 64.0f));
  float sn, cs;
  sincosf((float)pos * inv_freq, &sn, &cs);
  const float a = x1 * sc, b2 = x2 * sc;
  __hip_bfloat16 o1 = __float2bfloat16(a * cs - b2 * sn);
  __hip_bfloat16 o2 = __float2bfloat16(a * sn + b2 * cs);
  qkv[base + lane] = *(u16*)&o1;
  qkv[base + 64 + lane] = *(u16*)&o2;
}

// ---------------------------------------------------------------- flash attention
// 512 blocks = 8 XCD-groups (b,kvh) x 4 h x 16 j. Block processes q64-tiles
// (j, 31-j) sequentially: exactly 33 KV-tile iters each -> perfect balance.
// 4 waves = 2 q-groups x 2 k-halves; per-wave online (m,l,O) over its 32-k
// half; one in-LDS merge per phase. Swapped QK^T (S^T col=q), zero-shuffle
// PV via sigma-permuted V^T. K+V double-buffered, one barrier per iter.
__global__ __launch_bounds__(256, 2) void attn_kernel(const u16* __restrict__ qkv,
                                                      u16* __restrict__ ao) {
  __shared__ u16 Ks[2][64 * 128];   // [k][d], 16B chunks XORed by k&7
  __shared__ u16 Vt[2][128 * 64];   // [d][sigma(k)], chunks XORed by d&7

  const int t = threadIdx.x;
  const int lane = t & 63, w = t >> 6;
  const int l31 = lane & 31, hi = lane >> 5;
  const int qg = w >> 1, hi2 = w & 1;     // q-group, k-half

  const int bid = blockIdx.x;
  const int g = bid & 7;                  // XCD group = (b, kvh)
  const int b = g >> 2, kvh = g & 3;
  const int idx = bid >> 3;
  const int h = kvh * 4 + (idx & 3);
  const int j = idx >> 2;                 // 0..15 -> pair (j, 31-j)

  const int kcol = 2048 + kvh * 128, vcol = 2560 + kvh * 128;

  const int jv = t & 15, dc = t >> 4;     // V staging: rows 4jv..+3, d=dc*8..+7
  const int krow_s = t >> 4, kchk = t & 15;
  const int jv5 = jv & 7;
  const int vpos = 32 * (jv >> 3) + 16 * (jv5 >> 2) + 8 * (jv5 & 1)
                 + 4 * ((jv5 >> 1) & 1);  // sigma-permuted slot of k=4jv
  const int vchk = vpos >> 3, vsub = vpos & 7;

  const float sc2 = 0.08838834764831845f * 1.44269504088896340f;  // /sqrt(128)*log2e

#define STAGE_K(kb_, buf_) do {                                               \
    const size_t rb_ = (size_t)(b * 2048 + (kb_) * 64);                       \
    _Pragma("unroll")                                                         \
    for (int j_ = 0; j_ < 4; ++j_) {                                          \
      const int row_ = j_ * 16 + krow_s;                                      \
      GLD16(qkv + (rb_ + row_) * 3072 + kcol + ((kchk ^ (row_ & 7)) << 3),    \
            &Ks[buf_][(j_ * 256 + t) << 3]);                                  \
    } } while (0)

#define LOAD_V(kb_, vr_) do {                                                 \
    const u16* vp_ = qkv + (size_t)(b * 2048 + (kb_) * 64 + 4 * jv) * 3072    \
                     + vcol + dc * 8;                                         \
    vr_[0] = *(const bf16x8*)vp_;                                             \
    vr_[1] = *(const bf16x8*)(vp_ + 3072);                                    \
    vr_[2] = *(const bf16x8*)(vp_ + 6144);                                    \
    vr_[3] = *(const bf16x8*)(vp_ + 9216);                                    \
  } while (0)

#define WRITE_V(vr_, buf_) do {                                               \
    _Pragma("unroll")                                                         \
    for (int i_ = 0; i_ < 8; ++i_) {                                          \
      const int d_ = dc * 8 + i_;                                             \
      u64 val_ = (u64)(u16)vr_[0][i_] | ((u64)(u16)vr_[1][i_] << 16)          \
               | ((u64)(u16)vr_[2][i_] << 32) | ((u64)(u16)vr_[3][i_] << 48); \
      *(u64*)&Vt[buf_][d_ * 64 + (((vchk ^ i_) << 3) + vsub)] = val_;         \
    } } while (0)

  for (int ph = 0; ph < 2; ++ph) {
    const int qt64 = ph ? (31 - j) : j;
    const int q0 = qt64 * 64;
    const int nt = qt64 + 1;
    const int qrow = q0 + 32 * qg + l31;

    // Q fragments (B operand): col=q, k = st*16 + hi*8 + e
    bf16x8 qf[8];
    {
      const u16* qp = qkv + (size_t)(b * 2048 + qrow) * 3072 + h * 128 + hi * 8;
#pragma unroll
      for (int st = 0; st < 8; ++st) qf[st] = *(const bf16x8*)(qp + st * 16);
    }

    f32x16 o[4];
#pragma unroll
    for (int dt = 0; dt < 4; ++dt)
#pragma unroll
      for (int i = 0; i < 16; ++i) o[dt][i] = 0.f;
    float m2 = -1e30f, l = 0.f;

    // prologue: stage tile 0 into buffer 0
    {
      bf16x8 v0[4];
      LOAD_V(0, v0);
      STAGE_K(0, 0);
      WRITE_V(v0, 0);
    }

    for (int kb = 0; kb < nt; ++kb) {
      const int cur = kb & 1, nxt = cur ^ 1;
      __syncthreads();               // GLD[cur] drained, Vt[cur] written, all waves
      const bool have_next = (kb + 1 < nt);
      bf16x8 vn[4];
      if (have_next) {
        LOAD_V(kb + 1, vn);
        STAGE_K(kb + 1, nxt);
      }

      // ---- S^T = K_half Q^T  (rows k of this wave's 32-half, cols q)
      f32x16 s;
#pragma unroll
      for (int i = 0; i < 16; ++i) s[i] = 0.f;
      const int kbase = (32 * hi2 + l31) * 128;
      const int ksw = l31 & 7;
      __builtin_amdgcn_s_setprio(1);
#pragma unroll
      for (int st = 0; st < 8; ++st) {
        bf16x8 ka = *(const bf16x8*)&Ks[cur][kbase + (((2 * st + hi) ^ ksw) << 3)];
        s = MFMA32(ka, qf[st], s);
      }
      __builtin_amdgcn_s_setprio(0);

      // ---- mask + scale (exp2 domain), row max over this k-half
      float pm = -INFINITY;
      const bool nomask = (kb < qt64) || (hi2 == 0 && qg == 1);
      if (nomask) {
#pragma unroll
        for (int i = 0; i < 16; ++i) {
          s[i] *= sc2;
          pm = fmaxf(pm, s[i]);
        }
      } else {
#pragma unroll
        for (int i = 0; i < 16; ++i) {
          const int kr = kb * 64 + 32 * hi2 + (i & 3) + 8 * (i >> 2) + 4 * hi;
          s[i] = (kr <= qrow) ? s[i] * sc2 : -INFINITY;
          pm = fmaxf(pm, s[i]);
        }
      }
      pm = fmaxf(pm, __shfl_xor(pm, 32));
      // ---- defer-max rescale
      if (!__all(pm <= m2 + 8.f)) {
        const float m2n = fmaxf(m2, pm);
        const float fc = exp2f(m2 - m2n);
        m2 = m2n; l *= fc;
#pragma unroll
        for (int dt = 0; dt < 4; ++dt)
#pragma unroll
          for (int i = 0; i < 16; ++i) o[dt][i] *= fc;
      }
      // ---- P = exp2(z - m2), local sum (cross-hi deferred to epilogue)
      float sum = 0.f;
#pragma unroll
      for (int i = 0; i < 16; ++i) { s[i] = exp2f(s[i] - m2); sum += s[i]; }
      l += sum;
      // ---- P C-regs -> B-operand directly (sigma permutation, no shuffles)
      union PB { u32 wd[4]; bf16x8 v; } p0u, p1u;
#pragma unroll
      for (int q_ = 0; q_ < 4; ++q_) {
        p0u.wd[q_] = pkbf(s[2 * q_],     s[2 * q_ + 1]);
        p1u.wd[q_] = pkbf(s[8 + 2 * q_], s[8 + 2 * q_ + 1]);
      }
      // ---- O^T += V^T_half P_half  (rows d, cols q)
      __builtin_amdgcn_s_setprio(1);
#pragma unroll
      for (int dt = 0; dt < 4; ++dt) {
        const int vrow = (dt * 32 + l31) * 64;
        const int dsw = l31 & 7;
        bf16x8 va0 = *(const bf16x8*)&Vt[cur][vrow + (((4 * hi2 + hi) ^ dsw) << 3)];
        o[dt] = MFMA32(va0, p0u.v, o[dt]);
        bf16x8 va1 = *(const bf16x8*)&Vt[cur][vrow + (((4 * hi2 + 2 + hi) ^ dsw) << 3)];
        o[dt] = MFMA32(va1, p1u.v, o[dt]);
      }
      __builtin_amdgcn_s_setprio(0);

      if (have_next) WRITE_V(vn, nxt);
    }

    // ---- in-block merge of the two k-halves (per q-group)
    __syncthreads();                 // all compute done; Ks/Vt reusable
    const float l_tot = l + __shfl_xor(l, 32);
    float* Mrg = (float*)&Ks[0][0];  // [qg][dt][q=l31][hi*16+reg], chunk-XOR sw
    float* Mlb = (float*)&Vt[0][0];  // [qg][{m:0,l:32}+q]
    const int sw8 = l31 & 7;
    if (hi2) {
#pragma unroll
      for (int dt = 0; dt < 4; ++dt) {
        const int rbase = ((qg * 4 + dt) * 32 + l31) * 32;
#pragma unroll
        for (int m_ = 0; m_ < 4; ++m_) {
          f32x4 cv;
          cv[0] = o[dt][4 * m_ + 0]; cv[1] = o[dt][4 * m_ + 1];
          cv[2] = o[dt][4 * m_ + 2]; cv[3] = o[dt][4 * m_ + 3];
          *(f32x4*)&Mrg[rbase + (((hi * 4 + m_) ^ sw8) << 2)] = cv;
        }
      }
      if (hi == 0) {
        Mlb[qg * 64 + l31] = m2;
        Mlb[qg * 64 + 32 + l31] = l_tot;
      }
    }
    __syncthreads();
    if (!hi2) {
      const float m1 = Mlb[qg * 64 + l31];
      const float l1 = Mlb[qg * 64 + 32 + l31];
      const float ms = fmaxf(m2, m1);
      const float w0 = exp2f(m2 - ms), w1 = exp2f(m1 - ms);
      const float inv = 1.f / (w0 * l_tot + w1 * l1);
      const float a0 = w0 * inv, a1 = w1 * inv;
      const size_t orow = (size_t)(b * 2048 + qrow) * 2048 + h * 128;
#pragma unroll
      for (int dt = 0; dt < 4; ++dt) {
        const int rbase = ((qg * 4 + dt) * 32 + l31) * 32;
#pragma unroll
        for (int m_ = 0; m_ < 4; ++m_) {
          f32x4 o1v = *(const f32x4*)&Mrg[rbase + (((hi * 4 + m_) ^ sw8) << 2)];
          u64 val = 0;
#pragma unroll
          for (int r = 0; r < 4; ++r) {
            __hip_bfloat16 hb =
                __float2bfloat16(a0 * o[dt][4 * m_ + r] + a1 * o1v[r]);
            val |= (u64)(*(u16*)&hb) << (16 * r);
          }
          *(u64*)&ao[orow + dt * 32 + 8 * m_ + 4 * hi] = val;
        }
      }
    }
    if (ph == 0) __syncthreads();    // protect Mrg/Mlb before phase-B staging
  }
#undef STAGE_K
#undef LOAD_V
#undef WRITE_V
}

// ---------------------------------------------------------------- launch
extern "C" void kernel_launch(void* const* d_in, const int* in_sizes, int n_in,
                              void* d_out, int out_size, void* d_ws, size_t ws_size,
                              hipStream_t stream) {
  const float* x  = (const float*)d_in[0];
  const float* wq = (const float*)d_in[2];
  const float* wk = (const float*)d_in[3];
  const float* wv = (const float*)d_in[4];
  const float* wo = (const float*)d_in[5];
  float* out = (float*)d_out;

  u16* xb   = (u16*)d_ws;                       // x bf16   [4096][2048]
  u16* wqkv = xb + (size_t)8388608;             // W bf16   [3072][2048]
  u16* qkv  = wqkv + (size_t)6291456;           // qkv      [4096][3072]
  u16* ao   = xb;                               // attn out [4096][2048] (reuse xb)
  u16* wob  = wqkv;                             // wo bf16  [2048][2048] (reuse)

  cast_f32_bf16<<<8192, 256, 0, stream>>>(x,  xb,   2097152);
  cast_f32_bf16<<<4096, 256, 0, stream>>>(wq, wqkv, 1048576);
  cast_f32_bf16<<<1024, 256, 0, stream>>>(wk, wqkv + (size_t)4194304, 262144);
  cast_f32_bf16<<<1024, 256, 0, stream>>>(wv, wqkv + (size_t)5242880, 262144);

  gemm_bt<u16><<<dim3(24, 32), 256, 0, stream>>>(xb, wqkv, qkv, 4096, 3072, 2048);

  cast_f32_bf16<<<4096, 256, 0, stream>>>(wo, wob, 1048576);

  rmsrope_kernel<<<20480, 256, 0, stream>>>(qkv);

  attn_kernel<<<512, 256, 0, stream>>>(qkv, ao);

  gemm_bt<float><<<dim3(16, 32), 256, 0, stream>>>(ao, wob, out, 4096, 2048, 2048);
}